// Round 15
// baseline (432.923 us; speedup 1.0000x reference)
//
#include <hip/hip_runtime.h>
#include <math.h>

#define B_ 8192
#define E_ 100
#define D_ 300
#define P_ 100
#define H_ 20
#define F_ 202   // 2P+2
#define NT 10    // K steps of 32 (300 padded to 320)
#define NWG 12800

typedef __attribute__((ext_vector_type(8))) short bf16x8;
typedef __attribute__((ext_vector_type(8))) _Float16 f16x8;
typedef __attribute__((ext_vector_type(4))) float f32x4;
typedef __attribute__((ext_vector_type(8))) unsigned short us8;

// ---- workspace layout (bytes) ----
#define WG_OFF 0                          // wgate [B][E] f32       (3,276,800)
#define AB_OFF 3276800                    // A tiles                (20,971,520)
#define W1_OFF (AB_OFF + 20971520)        // B tiles                (14,336,000)
#define WH2_OFF (W1_OFF + 14336000)       // wh2 [E][2][20][232] f16 (1,856,000)
#define PD_OFF (WH2_OFF + 1856000)        // pd [E][B] f32          (3,276,800)
#define WS_ALL (PD_OFF + 3276800)         // 43,717,120 B

__device__ __forceinline__ unsigned short f2bf(float f) {
    unsigned int u = __float_as_uint(f);
    u = (u + 0x7FFF + ((u >> 16) & 1)) >> 16;   // RNE
    return (unsigned short)u;
}
__device__ __forceinline__ float bf2f(unsigned short h) {
    return __uint_as_float(((unsigned int)h) << 16);
}

#define GLOAD16(g, l) \
    __builtin_amdgcn_global_load_lds((const __attribute__((address_space(1))) unsigned int*)(g), \
                                     (__attribute__((address_space(3))) unsigned int*)(l), 16, 0, 0)

// ---------------------------------------------------------------------------
// prep: x,y -> split bf16 A-tiles. tile(rb,t) = [2][4 kg][128 row][8 k] (proven)
// ---------------------------------------------------------------------------
__global__ __launch_bounds__(256) void prep_xy(const float* __restrict__ x,
                                               const float* __restrict__ y,
                                               unsigned short* __restrict__ ab2)
{
    const int bi = blockIdx.x;               // rb*10 + t
    const int rb = bi / NT, t = bi - rb * NT;
    for (int s = threadIdx.x; s < 512; s += 256) {
        const int kg = s >> 7, row = s & 127;
        const float* src = ((row < 64) ? x : y) + (size_t)(rb * 64 + (row & 63)) * D_;
        const int k0 = t * 32 + kg * 8;
        us8 hi, lo;
        #pragma unroll
        for (int j = 0; j < 8; ++j) {
            const int k = k0 + j;
            const float v = (k < D_) ? src[k] : 0.f;
            const unsigned short h = f2bf(v);
            hi[j] = h;
            lo[j] = f2bf(v - bf2f(h));
        }
        unsigned short* tb = ab2 + (size_t)bi * 8192;
        *(us8*)(tb + (size_t)s * 8)         = hi;
        *(us8*)(tb + (size_t)(512 + s) * 8) = lo;
    }
}

// ---------------------------------------------------------------------------
// prep: W1 -> split bf16 B-tiles. tile(e,t) = [2][4 kg][112 p][8 k] (proven)
// ---------------------------------------------------------------------------
__global__ __launch_bounds__(256) void prep_w1(const float* __restrict__ w1,
                                               unsigned short* __restrict__ w1b2)
{
    const int bi = blockIdx.x;               // e*10 + t
    const int e = bi / NT, t = bi - e * NT;
    for (int s = threadIdx.x; s < 448; s += 256) {
        const int kg = s / 112, p = s - kg * 112;
        const int k0 = t * 32 + kg * 8;
        us8 hi, lo;
        #pragma unroll
        for (int j = 0; j < 8; ++j) {
            const int k = k0 + j;
            const float v = (p < P_ && k < D_) ? w1[((size_t)e * D_ + k) * P_ + p] : 0.f;
            const unsigned short h = f2bf(v);
            hi[j] = h;
            lo[j] = f2bf(v - bf2f(h));
        }
        unsigned short* tb = w1b2 + (size_t)bi * 7168;
        *(us8*)(tb + (size_t)s * 8)         = hi;
        *(us8*)(tb + (size_t)(448 + s) * 8) = lo;
    }
}

// ---------------------------------------------------------------------------
// prep: wh -> split fp16 wh^T: wh2[e][part][h][232] (values = R10 staging)
// ---------------------------------------------------------------------------
__global__ __launch_bounds__(256) void prep_wh(const float* __restrict__ wh,
                                               _Float16* __restrict__ wh2)
{
    const int e = blockIdx.x;
    for (int k = threadIdx.x; k < 20 * 232; k += 256) {
        const int h = k / 232, f = k - h * 232;
        const float v = (f < F_) ? wh[((size_t)e * F_ + f) * H_ + h] : 0.f;
        const _Float16 vh = (_Float16)v;
        wh2[(size_t)e * 9280 + k]        = vh;
        wh2[(size_t)e * 9280 + 4640 + k] = (_Float16)(v - (float)vh);
    }
}

// ---------------------------------------------------------------------------
// gating softmax v2: 256 blocks x 32 rows. wall chunk-staged in LDS so total
// wall traffic drops 983 MB -> 30 MB. Per-(row,e) z keeps the serial-d fma
// order (bit-identical); only the sum-reduction tree order changes (~1e-7).
// ---------------------------------------------------------------------------
__global__ __launch_bounds__(256) void gate_kernel(
    const float* __restrict__ x, const float* __restrict__ y,
    const float* __restrict__ wall, float* __restrict__ wgate)
{
    __shared__ float swall[75][104];   // e-padded with zeros
    __shared__ float ss[32][76];
    const int tid = threadIdx.x;
    const int r = tid >> 3, g = tid & 7;   // row-in-block, 8-thread expert group
    const int b0 = blockIdx.x * 32;

    float z[13];
    #pragma unroll
    for (int i = 0; i < 13; ++i) z[i] = 0.f;

    for (int dc = 0; dc < D_; dc += 75) {
        __syncthreads();
        for (int k = tid; k < 32 * 75; k += 256) {
            const int rr = k / 75, dd = k - rr * 75;
            ss[rr][dd] = x[(size_t)(b0 + rr) * D_ + dc + dd]
                       + y[(size_t)(b0 + rr) * D_ + dc + dd];
        }
        for (int k = tid; k < 75 * 104; k += 256) {
            const int dd = k / 104, e = k - dd * 104;
            swall[dd][e] = (e < E_) ? wall[(size_t)(dc + dd) * E_ + e] : 0.f;
        }
        __syncthreads();
        for (int dd = 0; dd < 75; ++dd) {
            const float sv = ss[r][dd];
            #pragma unroll
            for (int i = 0; i < 13; ++i)
                z[i] += sv * swall[dd][g * 13 + i];
        }
    }
    #pragma unroll
    for (int i = 0; i < 13; ++i)
        if (g * 13 + i >= E_) z[i] = -INFINITY;

    float m = z[0];
    #pragma unroll
    for (int i = 1; i < 13; ++i) m = fmaxf(m, z[i]);
    m = fmaxf(m, __shfl_xor(m, 1));
    m = fmaxf(m, __shfl_xor(m, 2));
    m = fmaxf(m, __shfl_xor(m, 4));

    float ev[13];
    float sum = 0.f;
    #pragma unroll
    for (int i = 0; i < 13; ++i) {
        ev[i] = (g * 13 + i < E_) ? expf(z[i] - m) : 0.f;
        sum += ev[i];
    }
    sum += __shfl_xor(sum, 1);
    sum += __shfl_xor(sum, 2);
    sum += __shfl_xor(sum, 4);

    const int b = b0 + r;
    #pragma unroll
    for (int i = 0; i < 13; ++i) {
        const int e = g * 13 + i;
        if (e < E_) wgate[(size_t)b * E_ + e] = ev[i] / sum;
    }
}

// ---------------------------------------------------------------------------
// main fused kernel: 1-D grid 12800, 256 threads (4 waves). (R12 proven 346us)
// MODE=1: phase-C B-frags from global wh2 (L2-hot), LDS 29,696 B, VGPR 64,
//   ~4 blocks/CU. MODE=0: fallback (swh2 in LDS, 48,256 B, atomic out).
// XCD swizzle v2 (rb-slice per XCD keeps A L2-resident). Numerics frozen.
// R15 deltas vs R12: wave-private pad-zeroing + post-phase-B barrier removed
// (wave-privacy of featl rows PROVEN by R13's barrier-free exact-match run).
// ---------------------------------------------------------------------------
template<int MODE>
__global__ __launch_bounds__(256, (MODE == 1) ? 4 : 3) void moe_mfma_kernel(
    const float* __restrict__ tag,
    const unsigned short* __restrict__ ab2,
    const unsigned short* __restrict__ w1b2,
    const _Float16* __restrict__ wh2g,
    const float* __restrict__ b1,
    const float* __restrict__ wh,
    const float* __restrict__ hb,
    const float* __restrict__ wo,
    const float* __restrict__ ob,
    const float* __restrict__ wgate,
    float* __restrict__ pd,
    float* __restrict__ out)
{
    __shared__ __align__(16) char smem[(MODE == 1) ? 29696 : 48256];
    // phase A view: B double-buffer (dead after phase A)
    unsigned short (*Bw_lds)[7168] = (unsigned short (*)[7168])smem;   // 2 x 14,336 B
    // phase B/C view: featl overlays the staging region
    _Float16 (*featl)[232] = (_Float16 (*)[232])smem;                  // 29,696 B
    // MODE=0 only: swh2 beyond featl
    _Float16 (*swh2)[20][232] = (_Float16 (*)[20][232])(smem + 29696); // 18,560 B

    const int tid  = threadIdx.x;
    const int lane = tid & 63, w = tid >> 6;

    // XCD-aware bijective swizzle v2: rb slice per XCD, e advances slowly.
    const int bid = blockIdx.x;
    const int rb = ((bid & 7) << 4) | ((bid >> 3) & 15);
    const int e  = bid >> 7;
    const int b0 = rb * 64;
    const int li = lane & 15, kgq = lane >> 4;

    if constexpr (MODE == 0) {
        // stage wh[e] as split fp16, transposed (hides under phase A)
        for (int k = tid; k < 20 * 232; k += 256) {
            const int h = k / 232, f = k - h * 232;
            const float v = (f < F_) ? wh[((size_t)e * F_ + f) * H_ + h] : 0.f;
            const _Float16 vh = (_Float16)v;
            (*swh2)[h][f] = vh;
            swh2[1][h][f] = (_Float16)(v - (float)vh);
        }
    }

    f32x4 accx[7], accy[7];
    #pragma unroll
    for (int ni = 0; ni < 7; ++ni) {
        accx[ni] = (f32x4){0.f, 0.f, 0.f, 0.f};
        accy[ni] = (f32x4){0.f, 0.f, 0.f, 0.f};
    }

    // per-lane frag bases (ushort units) within a tile
    const int a_base = (kgq * 128 + w * 16 + li) * 8;
    const int b_base = (kgq * 112 + li) * 8;

    // A-frag register double-buffer: [parity][xh, xl, yh, yl]
    bf16x8 areg[2][4];
    auto loadA = [&](int kt, int pb) {
        const unsigned short* tb = ab2 + (size_t)(rb * NT + kt) * 8192 + a_base;
        areg[pb][0] = *(const bf16x8*)(tb);          // x hi
        areg[pb][1] = *(const bf16x8*)(tb + 4096);   // x lo
        areg[pb][2] = *(const bf16x8*)(tb + 512);    // y hi
        areg[pb][3] = *(const bf16x8*)(tb + 4608);   // y lo
    };
    auto stageB = [&](int tt, int bb) {
        const unsigned short* bbase = w1b2 + (size_t)(e * NT + tt) * 7168 + lane * 8;
        #pragma unroll
        for (int k = 0; k < 4; ++k) {
            const int i = w + 4 * k;           // wave-uniform, 0..15; 14 used
            if (i < 14) GLOAD16(bbase + i * 512, &Bw_lds[bb][i * 512]);
        }
    };

    // -------- phase A: B-dbuf + A-reg pipeline, 1 barrier per k-tile --------
    stageB(0, 0);
    loadA(0, 0);
    __syncthreads();                            // vmcnt drain -> Bw[0] ready
    #pragma unroll
    for (int kt = 0; kt < NT; ++kt) {
        const int cb = kt & 1, nb = cb ^ 1;
        if (kt < NT - 1) {
            stageB(kt + 1, nb);                 // DMA into other buffer
            loadA(kt + 1, nb);                  // regs for next tile (latency under MFMAs)
        }
        const bf16x8 axh = areg[cb][0];
        const bf16x8 axl = areg[cb][1];
        const bf16x8 ayh = areg[cb][2];
        const bf16x8 ayl = areg[cb][3];
        #pragma unroll
        for (int ni = 0; ni < 7; ++ni) {
            const bf16x8 bh = *(const bf16x8*)(&Bw_lds[cb][b_base + ni * 128]);
            const bf16x8 bl = *(const bf16x8*)(&Bw_lds[cb][b_base + ni * 128 + 3584]);
            accx[ni] = __builtin_amdgcn_mfma_f32_16x16x32_bf16(axh, bh, accx[ni], 0, 0, 0);
            accx[ni] = __builtin_amdgcn_mfma_f32_16x16x32_bf16(axl, bh, accx[ni], 0, 0, 0);
            accx[ni] = __builtin_amdgcn_mfma_f32_16x16x32_bf16(axh, bl, accx[ni], 0, 0, 0);
            accy[ni] = __builtin_amdgcn_mfma_f32_16x16x32_bf16(ayh, bh, accy[ni], 0, 0, 0);
            accy[ni] = __builtin_amdgcn_mfma_f32_16x16x32_bf16(ayl, bh, accy[ni], 0, 0, 0);
            accy[ni] = __builtin_amdgcn_mfma_f32_16x16x32_bf16(ayh, bl, accy[ni], 0, 0, 0);
        }
        __syncthreads();     // waves done with Bw[cb]; Bw[nb] staging landed
    }

    // -------- staging dead: featl takes over (wave-private rows w*16..+15) ----
    for (int idx = lane; idx < 16 * 30; idx += 64)
        featl[w * 16 + idx / 30][202 + idx % 30] = (_Float16)0.f;

    // -------- phase B: bias, feat, cos (frozen arithmetic) --------
    float pxx[4] = {0, 0, 0, 0}, pyy[4] = {0, 0, 0, 0}, pxy[4] = {0, 0, 0, 0};
    #pragma unroll
    for (int ni = 0; ni < 7; ++ni) {
        const int c = ni * 16 + li;
        if (c < P_) {
            const float bp = b1[(size_t)e * P_ + c];
            #pragma unroll
            for (int j = 0; j < 4; ++j) {
                const float xv = accx[ni][j] + bp;
                const float yv = accy[ni][j] + bp;
                const int r = w * 16 + kgq * 4 + j;   // C-frag row (m89 layout)
                featl[r][1 + c]   = (_Float16)(xv + yv);
                featl[r][101 + c] = (_Float16)fabsf(xv - yv);
                pxx[j] += xv * xv; pyy[j] += yv * yv; pxy[j] += xv * yv;
            }
        }
    }
    #pragma unroll
    for (int j = 0; j < 4; ++j) {
        #pragma unroll
        for (int m = 1; m < 16; m <<= 1) {
            pxx[j] += __shfl_xor(pxx[j], m);
            pyy[j] += __shfl_xor(pyy[j], m);
            pxy[j] += __shfl_xor(pxy[j], m);
        }
    }
    if (li == 0) {
        #pragma unroll
        for (int j = 0; j < 4; ++j) {
            const int r = w * 16 + kgq * 4 + j;
            const float nx = fmaxf(sqrtf(pxx[j]), 1e-8f);
            const float ny = fmaxf(sqrtf(pyy[j]), 1e-8f);
            featl[r][0]   = (_Float16)(pxy[j] / (nx * ny));
            featl[r][201] = (_Float16)tag[b0 + r];
        }
    }
    // NO barrier: featl rows are wave-private (proven R13); same-wave LDS
    // ordering is program-order via compiler lgkmcnt waits.

    // -------- phase C: hidden (202->20) via fp16 MFMA + out (20->1) --------
    const int h1 = 16 + li;
    const bool v1 = (h1 < H_);
    const int h1c = v1 ? h1 : (H_ - 1);     // clamped in-bounds row for invalid lanes
    const _Float16* whp = wh2g + (size_t)e * 9280;

    f32x4 acc0 = (f32x4){0.f, 0.f, 0.f, 0.f};
    f32x4 acc1 = (f32x4){0.f, 0.f, 0.f, 0.f};
    #pragma unroll
    for (int kt = 0; kt < 7; ++kt) {
        const int ko = kt * 32 + kgq * 8;
        const f16x8 af = *(const f16x8*)(&featl[w * 16 + li][ko]);
        f16x8 b0h, b0l, b1h, b1l;
        if constexpr (MODE == 1) {
            b0h = *(const f16x8*)(whp + li * 232 + ko);
            b0l = *(const f16x8*)(whp + 4640 + li * 232 + ko);
            b1h = *(const f16x8*)(whp + h1c * 232 + ko);
            b1l = *(const f16x8*)(whp + 4640 + h1c * 232 + ko);
        } else {
            b0h = *(const f16x8*)(&(*swh2)[li][ko]);
            b0l = *(const f16x8*)(&swh2[1][li][ko]);
            b1h = *(const f16x8*)(&(*swh2)[h1c][ko]);
            b1l = *(const f16x8*)(&swh2[1][h1c][ko]);
        }
        if (!v1) {                              // zero pad-cols 20..31
            b1h = (f16x8)(_Float16)0.f;
            b1l = (f16x8)(_Float16)0.f;
        }
        acc0 = __builtin_amdgcn_mfma_f32_16x16x32_f16(af, b0h, acc0, 0, 0, 0);
        acc0 = __builtin_amdgcn_mfma_f32_16x16x32_f16(af, b0l, acc0, 0, 0, 0);
        acc1 = __builtin_amdgcn_mfma_f32_16x16x32_f16(af, b1h, acc1, 0, 0, 0);
        acc1 = __builtin_amdgcn_mfma_f32_16x16x32_f16(af, b1l, acc1, 0, 0, 0);
    }

    // epilogue: bias + relu + wo, reduce over h (16 lanes), write pd/out
    const float hb0 = hb[(size_t)e * H_ + li];
    const float wo0 = wo[(size_t)e * H_ + li];
    const float hb1 = v1 ? hb[(size_t)e * H_ + h1] : 0.f;
    const float wo1 = v1 ? wo[(size_t)e * H_ + h1] : 0.f;
    #pragma unroll
    for (int j = 0; j < 4; ++j) {
        float t = fmaxf(acc0[j] + hb0, 0.f) * wo0;
        if (v1) t += fmaxf(acc1[j] + hb1, 0.f) * wo1;
        t += __shfl_xor(t, 1);
        t += __shfl_xor(t, 2);
        t += __shfl_xor(t, 4);
        t += __shfl_xor(t, 8);
        if (li == 0) {
            const int r = w * 16 + kgq * 4 + j;   // C-frag row
            const int b = b0 + r;
            const float v = wgate[(size_t)b * E_ + e] * (t + ob[e]);
            if (MODE == 1) pd[(size_t)e * B_ + b] = v;
            else           atomicAdd(&out[b], v);
        }
    }
}

// ---------------------------------------------------------------------------
// deterministic reduction over experts (fixed e-ascending order)
// ---------------------------------------------------------------------------
__global__ __launch_bounds__(256) void reduce_kernel(const float* __restrict__ pd,
                                                     float* __restrict__ out)
{
    const int b = blockIdx.x * 256 + threadIdx.x;
    float s = 0.f;
    for (int e = 0; e < E_; ++e) s += pd[(size_t)e * B_ + b];
    out[b] = s;
}

// ---------------------------------------------------------------------------
extern "C" void kernel_launch(void* const* d_in, const int* in_sizes, int n_in,
                              void* d_out, int out_size, void* d_ws, size_t ws_size,
                              hipStream_t stream)
{
    const float* x    = (const float*)d_in[0];
    const float* y    = (const float*)d_in[1];
    const float* tag  = (const float*)d_in[2];
    const float* w1   = (const float*)d_in[3];
    const float* b1   = (const float*)d_in[4];
    const float* wh   = (const float*)d_in[5];
    const float* hb   = (const float*)d_in[6];
    const float* wo   = (const float*)d_in[7];
    const float* ob   = (const float*)d_in[8];
    const float* wall = (const float*)d_in[9];

    float* out = (float*)d_out;
    char* ws = (char*)d_ws;
    float*          wgate = (float*)(ws + WG_OFF);
    unsigned short* ab2   = (unsigned short*)(ws + AB_OFF);
    unsigned short* w1b2  = (unsigned short*)(ws + W1_OFF);
    _Float16*       wh2   = (_Float16*)(ws + WH2_OFF);
    float*          pd    = (float*)(ws + PD_OFF);

    const bool full = (ws_size >= (size_t)WS_ALL);

    prep_xy<<<dim3(128 * NT), dim3(256), 0, stream>>>(x, y, ab2);
    prep_w1<<<dim3(E_ * NT), dim3(256), 0, stream>>>(w1, w1b2);
    gate_kernel<<<dim3(B_ / 32), dim3(256), 0, stream>>>(x, y, wall, wgate);

    if (full) {
        prep_wh<<<dim3(E_), dim3(256), 0, stream>>>(wh, wh2);
        moe_mfma_kernel<1><<<dim3(NWG), dim3(256), 0, stream>>>(
            tag, ab2, w1b2, wh2, b1, wh, hb, wo, ob, wgate, pd, out);
        reduce_kernel<<<dim3(B_ / 256), dim3(256), 0, stream>>>(pd, out);
    } else {
        hipMemsetAsync(out, 0, (size_t)B_ * sizeof(float), stream);
        moe_mfma_kernel<0><<<dim3(NWG), dim3(256), 0, stream>>>(
            tag, ab2, w1b2, wh2, b1, wh, hb, wo, ob, wgate, pd, out);
    }
}

// Round 16
// 416.599 us; speedup vs baseline: 1.0392x; 1.0392x over previous
//
#include <hip/hip_runtime.h>
#include <math.h>

#define B_ 8192
#define E_ 100
#define D_ 300
#define P_ 100
#define H_ 20
#define F_ 202   // 2P+2
#define NT 10    // K steps of 32 (300 padded to 320)
#define NWG 12800

typedef __attribute__((ext_vector_type(8))) short bf16x8;
typedef __attribute__((ext_vector_type(8))) _Float16 f16x8;
typedef __attribute__((ext_vector_type(4))) float f32x4;
typedef __attribute__((ext_vector_type(8))) unsigned short us8;

// ---- workspace layout (bytes) ----
#define WG_OFF 0                          // wgate [B][E] f32       (3,276,800)
#define AB_OFF 3276800                    // A tiles                (20,971,520)
#define W1_OFF (AB_OFF + 20971520)        // B tiles                (14,336,000)
#define WH2_OFF (W1_OFF + 14336000)       // wh2 [E][2][20][232] f16 (1,856,000)
#define PD_OFF (WH2_OFF + 1856000)        // pd [E][B] f32          (3,276,800)
#define WS_ALL (PD_OFF + 3276800)         // 43,717,120 B

__device__ __forceinline__ unsigned short f2bf(float f) {
    unsigned int u = __float_as_uint(f);
    u = (u + 0x7FFF + ((u >> 16) & 1)) >> 16;   // RNE
    return (unsigned short)u;
}
__device__ __forceinline__ float bf2f(unsigned short h) {
    return __uint_as_float(((unsigned int)h) << 16);
}

#define GLOAD16(g, l) \
    __builtin_amdgcn_global_load_lds((const __attribute__((address_space(1))) unsigned int*)(g), \
                                     (__attribute__((address_space(3))) unsigned int*)(l), 16, 0, 0)

// ---------------------------------------------------------------------------
// prep: x,y -> split bf16 A-tiles. tile(rb,t) = [2][4 kg][128 row][8 k] (proven)
// ---------------------------------------------------------------------------
__global__ __launch_bounds__(256) void prep_xy(const float* __restrict__ x,
                                               const float* __restrict__ y,
                                               unsigned short* __restrict__ ab2)
{
    const int bi = blockIdx.x;               // rb*10 + t
    const int rb = bi / NT, t = bi - rb * NT;
    for (int s = threadIdx.x; s < 512; s += 256) {
        const int kg = s >> 7, row = s & 127;
        const float* src = ((row < 64) ? x : y) + (size_t)(rb * 64 + (row & 63)) * D_;
        const int k0 = t * 32 + kg * 8;
        us8 hi, lo;
        #pragma unroll
        for (int j = 0; j < 8; ++j) {
            const int k = k0 + j;
            const float v = (k < D_) ? src[k] : 0.f;
            const unsigned short h = f2bf(v);
            hi[j] = h;
            lo[j] = f2bf(v - bf2f(h));
        }
        unsigned short* tb = ab2 + (size_t)bi * 8192;
        *(us8*)(tb + (size_t)s * 8)         = hi;
        *(us8*)(tb + (size_t)(512 + s) * 8) = lo;
    }
}

// ---------------------------------------------------------------------------
// prep: W1 -> split bf16 B-tiles. tile(e,t) = [2][4 kg][112 p][8 k] (proven)
// ---------------------------------------------------------------------------
__global__ __launch_bounds__(256) void prep_w1(const float* __restrict__ w1,
                                               unsigned short* __restrict__ w1b2)
{
    const int bi = blockIdx.x;               // e*10 + t
    const int e = bi / NT, t = bi - e * NT;
    for (int s = threadIdx.x; s < 448; s += 256) {
        const int kg = s / 112, p = s - kg * 112;
        const int k0 = t * 32 + kg * 8;
        us8 hi, lo;
        #pragma unroll
        for (int j = 0; j < 8; ++j) {
            const int k = k0 + j;
            const float v = (p < P_ && k < D_) ? w1[((size_t)e * D_ + k) * P_ + p] : 0.f;
            const unsigned short h = f2bf(v);
            hi[j] = h;
            lo[j] = f2bf(v - bf2f(h));
        }
        unsigned short* tb = w1b2 + (size_t)bi * 7168;
        *(us8*)(tb + (size_t)s * 8)         = hi;
        *(us8*)(tb + (size_t)(448 + s) * 8) = lo;
    }
}

// ---------------------------------------------------------------------------
// prep: wh -> split fp16 wh^T: wh2[e][part][h][232] (values = R10 staging)
// ---------------------------------------------------------------------------
__global__ __launch_bounds__(256) void prep_wh(const float* __restrict__ wh,
                                               _Float16* __restrict__ wh2)
{
    const int e = blockIdx.x;
    for (int k = threadIdx.x; k < 20 * 232; k += 256) {
        const int h = k / 232, f = k - h * 232;
        const float v = (f < F_) ? wh[((size_t)e * F_ + f) * H_ + h] : 0.f;
        const _Float16 vh = (_Float16)v;
        wh2[(size_t)e * 9280 + k]        = vh;
        wh2[(size_t)e * 9280 + 4640 + k] = (_Float16)(v - (float)vh);
    }
}

// ---------------------------------------------------------------------------
// gating softmax (fp32, proven R1-R12)
// ---------------------------------------------------------------------------
__global__ __launch_bounds__(128) void gate_kernel(
    const float* __restrict__ x, const float* __restrict__ y,
    const float* __restrict__ wall, float* __restrict__ wgate)
{
    __shared__ float s[D_];
    __shared__ float zv[128];
    __shared__ float red[128];
    const int b = blockIdx.x;
    const int tid = threadIdx.x;

    for (int d = tid; d < D_; d += 128)
        s[d] = x[(size_t)b * D_ + d] + y[(size_t)b * D_ + d];
    __syncthreads();

    float acc = 0.f;
    if (tid < E_)
        for (int d = 0; d < D_; ++d) acc += s[d] * wall[(size_t)d * E_ + tid];
    zv[tid] = (tid < E_) ? acc : -INFINITY;
    red[tid] = zv[tid];
    __syncthreads();
    for (int st = 64; st > 0; st >>= 1) {
        if (tid < st) red[tid] = fmaxf(red[tid], red[tid + st]);
        __syncthreads();
    }
    const float m = red[0];
    __syncthreads();
    const float ev = (tid < E_) ? expf(zv[tid] - m) : 0.f;
    red[tid] = ev;
    __syncthreads();
    for (int st = 64; st > 0; st >>= 1) {
        if (tid < st) red[tid] += red[tid + st];
        __syncthreads();
    }
    if (tid < E_) wgate[(size_t)b * E_ + tid] = ev / red[0];
}

// ---------------------------------------------------------------------------
// main fused kernel: 1-D grid 12800, 256 threads (4 waves). R12 structure.
// R16 delta vs R12: MODE=1 __launch_bounds__(256,3) (was (256,4)).
//   (256,4) squeezed VGPR to exactly 64 (8-wave boundary) with ~25 MB of
//   suspected light spill (WRITE 28.8 MB vs 3.2 MB pd). (256,3) lets the
//   compiler sit at its natural ~68 VGPR (R10 evidence); HW occupancy steps
//   at VGPR {64,128} -> 68 still gives 4 waves/SIMD -> same 4 blocks/CU,
//   zero spill. Everything else byte-identical to R12 (proven 346 us,
//   absmax exactly 0.015625).
// ---------------------------------------------------------------------------
template<int MODE>
__global__ __launch_bounds__(256, 3) void moe_mfma_kernel(
    const float* __restrict__ tag,
    const unsigned short* __restrict__ ab2,
    const unsigned short* __restrict__ w1b2,
    const _Float16* __restrict__ wh2g,
    const float* __restrict__ b1,
    const float* __restrict__ wh,
    const float* __restrict__ hb,
    const float* __restrict__ wo,
    const float* __restrict__ ob,
    const float* __restrict__ wgate,
    float* __restrict__ pd,
    float* __restrict__ out)
{
    __shared__ __align__(16) char smem[(MODE == 1) ? 29696 : 48256];
    // phase A view: B double-buffer (dead after phase A)
    unsigned short (*Bw_lds)[7168] = (unsigned short (*)[7168])smem;   // 2 x 14,336 B
    // phase B/C view: featl overlays the staging region
    _Float16 (*featl)[232] = (_Float16 (*)[232])smem;                  // 29,696 B
    // MODE=0 only: swh2 beyond featl
    _Float16 (*swh2)[20][232] = (_Float16 (*)[20][232])(smem + 29696); // 18,560 B

    const int tid  = threadIdx.x;
    const int lane = tid & 63, w = tid >> 6;

    // XCD-aware bijective swizzle v2: rb slice per XCD, e advances slowly.
    const int bid = blockIdx.x;
    const int rb = ((bid & 7) << 4) | ((bid >> 3) & 15);
    const int e  = bid >> 7;
    const int b0 = rb * 64;
    const int li = lane & 15, kgq = lane >> 4;

    if constexpr (MODE == 0) {
        // stage wh[e] as split fp16, transposed (hides under phase A)
        for (int k = tid; k < 20 * 232; k += 256) {
            const int h = k / 232, f = k - h * 232;
            const float v = (f < F_) ? wh[((size_t)e * F_ + f) * H_ + h] : 0.f;
            const _Float16 vh = (_Float16)v;
            (*swh2)[h][f] = vh;
            swh2[1][h][f] = (_Float16)(v - (float)vh);
        }
    }

    f32x4 accx[7], accy[7];
    #pragma unroll
    for (int ni = 0; ni < 7; ++ni) {
        accx[ni] = (f32x4){0.f, 0.f, 0.f, 0.f};
        accy[ni] = (f32x4){0.f, 0.f, 0.f, 0.f};
    }

    // per-lane frag bases (ushort units) within a tile
    const int a_base = (kgq * 128 + w * 16 + li) * 8;
    const int b_base = (kgq * 112 + li) * 8;

    // A-frag register double-buffer: [parity][xh, xl, yh, yl]
    bf16x8 areg[2][4];
    auto loadA = [&](int kt, int pb) {
        const unsigned short* tb = ab2 + (size_t)(rb * NT + kt) * 8192 + a_base;
        areg[pb][0] = *(const bf16x8*)(tb);          // x hi
        areg[pb][1] = *(const bf16x8*)(tb + 4096);   // x lo
        areg[pb][2] = *(const bf16x8*)(tb + 512);    // y hi
        areg[pb][3] = *(const bf16x8*)(tb + 4608);   // y lo
    };
    auto stageB = [&](int tt, int bb) {
        const unsigned short* bbase = w1b2 + (size_t)(e * NT + tt) * 7168 + lane * 8;
        #pragma unroll
        for (int k = 0; k < 4; ++k) {
            const int i = w + 4 * k;           // wave-uniform, 0..15; 14 used
            if (i < 14) GLOAD16(bbase + i * 512, &Bw_lds[bb][i * 512]);
        }
    };

    // -------- phase A: B-dbuf + A-reg pipeline, 1 barrier per k-tile --------
    stageB(0, 0);
    loadA(0, 0);
    __syncthreads();                            // vmcnt drain -> Bw[0] ready
    #pragma unroll
    for (int kt = 0; kt < NT; ++kt) {
        const int cb = kt & 1, nb = cb ^ 1;
        if (kt < NT - 1) {
            stageB(kt + 1, nb);                 // DMA into other buffer
            loadA(kt + 1, nb);                  // regs for next tile (latency under MFMAs)
        }
        const bf16x8 axh = areg[cb][0];
        const bf16x8 axl = areg[cb][1];
        const bf16x8 ayh = areg[cb][2];
        const bf16x8 ayl = areg[cb][3];
        #pragma unroll
        for (int ni = 0; ni < 7; ++ni) {
            const bf16x8 bh = *(const bf16x8*)(&Bw_lds[cb][b_base + ni * 128]);
            const bf16x8 bl = *(const bf16x8*)(&Bw_lds[cb][b_base + ni * 128 + 3584]);
            accx[ni] = __builtin_amdgcn_mfma_f32_16x16x32_bf16(axh, bh, accx[ni], 0, 0, 0);
            accx[ni] = __builtin_amdgcn_mfma_f32_16x16x32_bf16(axl, bh, accx[ni], 0, 0, 0);
            accx[ni] = __builtin_amdgcn_mfma_f32_16x16x32_bf16(axh, bl, accx[ni], 0, 0, 0);
            accy[ni] = __builtin_amdgcn_mfma_f32_16x16x32_bf16(ayh, bh, accy[ni], 0, 0, 0);
            accy[ni] = __builtin_amdgcn_mfma_f32_16x16x32_bf16(ayl, bh, accy[ni], 0, 0, 0);
            accy[ni] = __builtin_amdgcn_mfma_f32_16x16x32_bf16(ayh, bl, accy[ni], 0, 0, 0);
        }
        __syncthreads();     // waves done with Bw[cb]; Bw[nb] staging landed
    }

    // -------- staging region dead: featl takes over. zero k-pads [202..231] ---
    for (int k = tid; k < 64 * 30; k += 256) featl[k / 30][202 + k % 30] = (_Float16)0.f;

    // -------- phase B: bias, feat, cos (frozen) --------
    float pxx[4] = {0, 0, 0, 0}, pyy[4] = {0, 0, 0, 0}, pxy[4] = {0, 0, 0, 0};
    #pragma unroll
    for (int ni = 0; ni < 7; ++ni) {
        const int c = ni * 16 + li;
        if (c < P_) {
            const float bp = b1[(size_t)e * P_ + c];
            #pragma unroll
            for (int j = 0; j < 4; ++j) {
                const float xv = accx[ni][j] + bp;
                const float yv = accy[ni][j] + bp;
                const int r = w * 16 + kgq * 4 + j;   // C-frag row (m89 layout)
                featl[r][1 + c]   = (_Float16)(xv + yv);
                featl[r][101 + c] = (_Float16)fabsf(xv - yv);
                pxx[j] += xv * xv; pyy[j] += yv * yv; pxy[j] += xv * yv;
            }
        }
    }
    #pragma unroll
    for (int j = 0; j < 4; ++j) {
        #pragma unroll
        for (int m = 1; m < 16; m <<= 1) {
            pxx[j] += __shfl_xor(pxx[j], m);
            pyy[j] += __shfl_xor(pyy[j], m);
            pxy[j] += __shfl_xor(pxy[j], m);
        }
    }
    if (li == 0) {
        #pragma unroll
        for (int j = 0; j < 4; ++j) {
            const int r = w * 16 + kgq * 4 + j;
            const float nx = fmaxf(sqrtf(pxx[j]), 1e-8f);
            const float ny = fmaxf(sqrtf(pyy[j]), 1e-8f);
            featl[r][0]   = (_Float16)(pxy[j] / (nx * ny));
            featl[r][201] = (_Float16)tag[b0 + r];
        }
    }
    __syncthreads();

    // -------- phase C: hidden (202->20) via fp16 MFMA + out (20->1) --------
    const int h1 = 16 + li;
    const bool v1 = (h1 < H_);
    const int h1c = v1 ? h1 : (H_ - 1);     // clamped in-bounds row for invalid lanes
    const _Float16* whp = wh2g + (size_t)e * 9280;

    f32x4 acc0 = (f32x4){0.f, 0.f, 0.f, 0.f};
    f32x4 acc1 = (f32x4){0.f, 0.f, 0.f, 0.f};
    #pragma unroll
    for (int kt = 0; kt < 7; ++kt) {
        const int ko = kt * 32 + kgq * 8;
        const f16x8 af = *(const f16x8*)(&featl[w * 16 + li][ko]);
        f16x8 b0h, b0l, b1h, b1l;
        if constexpr (MODE == 1) {
            b0h = *(const f16x8*)(whp + li * 232 + ko);
            b0l = *(const f16x8*)(whp + 4640 + li * 232 + ko);
            b1h = *(const f16x8*)(whp + h1c * 232 + ko);
            b1l = *(const f16x8*)(whp + 4640 + h1c * 232 + ko);
        } else {
            b0h = *(const f16x8*)(&(*swh2)[li][ko]);
            b0l = *(const f16x8*)(&swh2[1][li][ko]);
            b1h = *(const f16x8*)(&(*swh2)[h1c][ko]);
            b1l = *(const f16x8*)(&swh2[1][h1c][ko]);
        }
        if (!v1) {                              // zero pad-cols 20..31
            b1h = (f16x8)(_Float16)0.f;
            b1l = (f16x8)(_Float16)0.f;
        }
        acc0 = __builtin_amdgcn_mfma_f32_16x16x32_f16(af, b0h, acc0, 0, 0, 0);
        acc0 = __builtin_amdgcn_mfma_f32_16x16x32_f16(af, b0l, acc0, 0, 0, 0);
        acc1 = __builtin_amdgcn_mfma_f32_16x16x32_f16(af, b1h, acc1, 0, 0, 0);
        acc1 = __builtin_amdgcn_mfma_f32_16x16x32_f16(af, b1l, acc1, 0, 0, 0);
    }

    // epilogue: bias + relu + wo, reduce over h (16 lanes), write pd/out
    const float hb0 = hb[(size_t)e * H_ + li];
    const float wo0 = wo[(size_t)e * H_ + li];
    const float hb1 = v1 ? hb[(size_t)e * H_ + h1] : 0.f;
    const float wo1 = v1 ? wo[(size_t)e * H_ + h1] : 0.f;
    #pragma unroll
    for (int j = 0; j < 4; ++j) {
        float t = fmaxf(acc0[j] + hb0, 0.f) * wo0;
        if (v1) t += fmaxf(acc1[j] + hb1, 0.f) * wo1;
        t += __shfl_xor(t, 1);
        t += __shfl_xor(t, 2);
        t += __shfl_xor(t, 4);
        t += __shfl_xor(t, 8);
        if (li == 0) {
            const int r = w * 16 + kgq * 4 + j;   // C-frag row
            const int b = b0 + r;
            const float v = wgate[(size_t)b * E_ + e] * (t + ob[e]);
            if (MODE == 1) pd[(size_t)e * B_ + b] = v;
            else           atomicAdd(&out[b], v);
        }
    }
}

// ---------------------------------------------------------------------------
// deterministic reduction over experts (fixed e-ascending order)
// ---------------------------------------------------------------------------
__global__ __launch_bounds__(256) void reduce_kernel(const float* __restrict__ pd,
                                                     float* __restrict__ out)
{
    const int b = blockIdx.x * 256 + threadIdx.x;
    float s = 0.f;
    for (int e = 0; e < E_; ++e) s += pd[(size_t)e * B_ + b];
    out[b] = s;
}

// ---------------------------------------------------------------------------
extern "C" void kernel_launch(void* const* d_in, const int* in_sizes, int n_in,
                              void* d_out, int out_size, void* d_ws, size_t ws_size,
                              hipStream_t stream)
{
    const float* x    = (const float*)d_in[0];
    const float* y    = (const float*)d_in[1];
    const float* tag  = (const float*)d_in[2];
    const float* w1   = (const float*)d_in[3];
    const float* b1   = (const float*)d_in[4];
    const float* wh   = (const float*)d_in[5];
    const float* hb   = (const float*)d_in[6];
    const float* wo   = (const float*)d_in[7];
    const float* ob   = (const float*)d_in[8];
    const float* wall = (const float*)d_in[9];

    float* out = (float*)d_out;
    char* ws = (char*)d_ws;
    float*          wgate = (float*)(ws + WG_OFF);
    unsigned short* ab2   = (unsigned short*)(ws + AB_OFF);
    unsigned short* w1b2  = (unsigned short*)(ws + W1_OFF);
    _Float16*       wh2   = (_Float16*)(ws + WH2_OFF);
    float*          pd    = (float*)(ws + PD_OFF);

    const bool full = (ws_size >= (size_t)WS_ALL);

    prep_xy<<<dim3(128 * NT), dim3(256), 0, stream>>>(x, y, ab2);
    prep_w1<<<dim3(E_ * NT), dim3(256), 0, stream>>>(w1, w1b2);
    gate_kernel<<<dim3(B_), dim3(128), 0, stream>>>(x, y, wall, wgate);

    if (full) {
        prep_wh<<<dim3(E_), dim3(256), 0, stream>>>(wh, wh2);
        moe_mfma_kernel<1><<<dim3(NWG), dim3(256), 0, stream>>>(
            tag, ab2, w1b2, wh2, b1, wh, hb, wo, ob, wgate, pd, out);
        reduce_kernel<<<dim3(B_ / 256), dim3(256), 0, stream>>>(pd, out);
    } else {
        hipMemsetAsync(out, 0, (size_t)B_ * sizeof(float), stream);
        moe_mfma_kernel<0><<<dim3(NWG), dim3(256), 0, stream>>>(
            tag, ab2, w1b2, wh2, b1, wh, hb, wo, ob, wgate, pd, out);
    }
}

// Round 17
// 406.356 us; speedup vs baseline: 1.0654x; 1.0252x over previous
//
#include <hip/hip_runtime.h>
#include <math.h>

#define B_ 8192
#define E_ 100
#define D_ 300
#define P_ 100
#define H_ 20
#define F_ 202   // 2P+2
#define NT 10    // K steps of 32 (300 padded to 320)
#define NWG 12800

typedef __attribute__((ext_vector_type(8))) short bf16x8;
typedef __attribute__((ext_vector_type(8))) _Float16 f16x8;
typedef __attribute__((ext_vector_type(4))) float f32x4;
typedef __attribute__((ext_vector_type(8))) unsigned short us8;

// ---- workspace layout (bytes) ----
#define WG_OFF 0                          // wgate [B][E] f32       (3,276,800)
#define AB_OFF 3276800                    // A tiles                (20,971,520)
#define W1_OFF (AB_OFF + 20971520)        // B tiles                (14,336,000)
#define WH2_OFF (W1_OFF + 14336000)       // wh2 [E][2][20][232] f16 (1,856,000)
#define PD_OFF (WH2_OFF + 1856000)        // pd [E][B] f32          (3,276,800)
#define WS_ALL (PD_OFF + 3276800)         // 43,717,120 B

__device__ __forceinline__ unsigned short f2bf(float f) {
    unsigned int u = __float_as_uint(f);
    u = (u + 0x7FFF + ((u >> 16) & 1)) >> 16;   // RNE
    return (unsigned short)u;
}
__device__ __forceinline__ float bf2f(unsigned short h) {
    return __uint_as_float(((unsigned int)h) << 16);
}

#define GLOAD16(g, l) \
    __builtin_amdgcn_global_load_lds((const __attribute__((address_space(1))) unsigned int*)(g), \
                                     (__attribute__((address_space(3))) unsigned int*)(l), 16, 0, 0)

// ---------------------------------------------------------------------------
// prep: x,y -> split bf16 A-tiles. tile(rb,t) = [2][4 kg][128 row][8 k] (proven)
// ---------------------------------------------------------------------------
__global__ __launch_bounds__(256) void prep_xy(const float* __restrict__ x,
                                               const float* __restrict__ y,
                                               unsigned short* __restrict__ ab2)
{
    const int bi = blockIdx.x;               // rb*10 + t
    const int rb = bi / NT, t = bi - rb * NT;
    for (int s = threadIdx.x; s < 512; s += 256) {
        const int kg = s >> 7, row = s & 127;
        const float* src = ((row < 64) ? x : y) + (size_t)(rb * 64 + (row & 63)) * D_;
        const int k0 = t * 32 + kg * 8;
        us8 hi, lo;
        #pragma unroll
        for (int j = 0; j < 8; ++j) {
            const int k = k0 + j;
            const float v = (k < D_) ? src[k] : 0.f;
            const unsigned short h = f2bf(v);
            hi[j] = h;
            lo[j] = f2bf(v - bf2f(h));
        }
        unsigned short* tb = ab2 + (size_t)bi * 8192;
        *(us8*)(tb + (size_t)s * 8)         = hi;
        *(us8*)(tb + (size_t)(512 + s) * 8) = lo;
    }
}

// ---------------------------------------------------------------------------
// prep: W1 -> split bf16 B-tiles. tile(e,t) = [2][4 kg][112 p][8 k] (proven)
// ---------------------------------------------------------------------------
__global__ __launch_bounds__(256) void prep_w1(const float* __restrict__ w1,
                                               unsigned short* __restrict__ w1b2)
{
    const int bi = blockIdx.x;               // e*10 + t
    const int e = bi / NT, t = bi - e * NT;
    for (int s = threadIdx.x; s < 448; s += 256) {
        const int kg = s / 112, p = s - kg * 112;
        const int k0 = t * 32 + kg * 8;
        us8 hi, lo;
        #pragma unroll
        for (int j = 0; j < 8; ++j) {
            const int k = k0 + j;
            const float v = (p < P_ && k < D_) ? w1[((size_t)e * D_ + k) * P_ + p] : 0.f;
            const unsigned short h = f2bf(v);
            hi[j] = h;
            lo[j] = f2bf(v - bf2f(h));
        }
        unsigned short* tb = w1b2 + (size_t)bi * 7168;
        *(us8*)(tb + (size_t)s * 8)         = hi;
        *(us8*)(tb + (size_t)(448 + s) * 8) = lo;
    }
}

// ---------------------------------------------------------------------------
// prep: wh -> split fp16 wh^T: wh2[e][part][h][232] (values = R10 staging)
// ---------------------------------------------------------------------------
__global__ __launch_bounds__(256) void prep_wh(const float* __restrict__ wh,
                                               _Float16* __restrict__ wh2)
{
    const int e = blockIdx.x;
    for (int k = threadIdx.x; k < 20 * 232; k += 256) {
        const int h = k / 232, f = k - h * 232;
        const float v = (f < F_) ? wh[((size_t)e * F_ + f) * H_ + h] : 0.f;
        const _Float16 vh = (_Float16)v;
        wh2[(size_t)e * 9280 + k]        = vh;
        wh2[(size_t)e * 9280 + 4640 + k] = (_Float16)(v - (float)vh);
    }
}

// ---------------------------------------------------------------------------
// gating softmax (fp32, proven R1-R12)
// ---------------------------------------------------------------------------
__global__ __launch_bounds__(128) void gate_kernel(
    const float* __restrict__ x, const float* __restrict__ y,
    const float* __restrict__ wall, float* __restrict__ wgate)
{
    __shared__ float s[D_];
    __shared__ float zv[128];
    __shared__ float red[128];
    const int b = blockIdx.x;
    const int tid = threadIdx.x;

    for (int d = tid; d < D_; d += 128)
        s[d] = x[(size_t)b * D_ + d] + y[(size_t)b * D_ + d];
    __syncthreads();

    float acc = 0.f;
    if (tid < E_)
        for (int d = 0; d < D_; ++d) acc += s[d] * wall[(size_t)d * E_ + tid];
    zv[tid] = (tid < E_) ? acc : -INFINITY;
    red[tid] = zv[tid];
    __syncthreads();
    for (int st = 64; st > 0; st >>= 1) {
        if (tid < st) red[tid] = fmaxf(red[tid], red[tid + st]);
        __syncthreads();
    }
    const float m = red[0];
    __syncthreads();
    const float ev = (tid < E_) ? expf(zv[tid] - m) : 0.f;
    red[tid] = ev;
    __syncthreads();
    for (int st = 64; st > 0; st >>= 1) {
        if (tid < st) red[tid] += red[tid + st];
        __syncthreads();
    }
    if (tid < E_) wgate[(size_t)b * E_ + tid] = ev / red[0];
}

// ---------------------------------------------------------------------------
// main fused kernel: 1-D grid 12800, 256 threads (4 waves). R12 EXACT revert
// (proven 346 us moe, absmax exactly 0.015625).
// MODE=1: phase-C B-frags from global wh2 (L2-hot), LDS 29,696 B.
//   __launch_bounds__(256,4): VGPR squeezed to 64 with ~25 MB light spill
//   (72 GB/s amortized — cheap) buying 4 blocks/CU. R16 proved the no-spill
//   (256,3) alternative loses 34 us to the lost 4th block. Light spill <<
//   occupancy on this latency-bound shape.
// MODE=0: fallback (swh2 in LDS, 48,256 B, 3 blocks/CU, atomic out).
// XCD swizzle v2: rb-slice per XCD keeps the 100x-reused A slice L2-resident
// (R9's e-major swizzle thrashed: 1.09 GB fabric traffic).
// ---------------------------------------------------------------------------
template<int MODE>
__global__ __launch_bounds__(256, (MODE == 1) ? 4 : 3) void moe_mfma_kernel(
    const float* __restrict__ tag,
    const unsigned short* __restrict__ ab2,
    const unsigned short* __restrict__ w1b2,
    const _Float16* __restrict__ wh2g,
    const float* __restrict__ b1,
    const float* __restrict__ wh,
    const float* __restrict__ hb,
    const float* __restrict__ wo,
    const float* __restrict__ ob,
    const float* __restrict__ wgate,
    float* __restrict__ pd,
    float* __restrict__ out)
{
    __shared__ __align__(16) char smem[(MODE == 1) ? 29696 : 48256];
    // phase A view: B double-buffer (dead after phase A)
    unsigned short (*Bw_lds)[7168] = (unsigned short (*)[7168])smem;   // 2 x 14,336 B
    // phase B/C view: featl overlays the staging region
    _Float16 (*featl)[232] = (_Float16 (*)[232])smem;                  // 29,696 B
    // MODE=0 only: swh2 beyond featl
    _Float16 (*swh2)[20][232] = (_Float16 (*)[20][232])(smem + 29696); // 18,560 B

    const int tid  = threadIdx.x;
    const int lane = tid & 63, w = tid >> 6;

    // XCD-aware bijective swizzle v2: rb slice per XCD, e advances slowly.
    const int bid = blockIdx.x;
    const int rb = ((bid & 7) << 4) | ((bid >> 3) & 15);
    const int e  = bid >> 7;
    const int b0 = rb * 64;
    const int li = lane & 15, kgq = lane >> 4;

    if constexpr (MODE == 0) {
        // stage wh[e] as split fp16, transposed (hides under phase A)
        for (int k = tid; k < 20 * 232; k += 256) {
            const int h = k / 232, f = k - h * 232;
            const float v = (f < F_) ? wh[((size_t)e * F_ + f) * H_ + h] : 0.f;
            const _Float16 vh = (_Float16)v;
            (*swh2)[h][f] = vh;
            swh2[1][h][f] = (_Float16)(v - (float)vh);
        }
    }

    f32x4 accx[7], accy[7];
    #pragma unroll
    for (int ni = 0; ni < 7; ++ni) {
        accx[ni] = (f32x4){0.f, 0.f, 0.f, 0.f};
        accy[ni] = (f32x4){0.f, 0.f, 0.f, 0.f};
    }

    // per-lane frag bases (ushort units) within a tile
    const int a_base = (kgq * 128 + w * 16 + li) * 8;
    const int b_base = (kgq * 112 + li) * 8;

    // A-frag register double-buffer: [parity][xh, xl, yh, yl]
    bf16x8 areg[2][4];
    auto loadA = [&](int kt, int pb) {
        const unsigned short* tb = ab2 + (size_t)(rb * NT + kt) * 8192 + a_base;
        areg[pb][0] = *(const bf16x8*)(tb);          // x hi
        areg[pb][1] = *(const bf16x8*)(tb + 4096);   // x lo
        areg[pb][2] = *(const bf16x8*)(tb + 512);    // y hi
        areg[pb][3] = *(const bf16x8*)(tb + 4608);   // y lo
    };
    auto stageB = [&](int tt, int bb) {
        const unsigned short* bbase = w1b2 + (size_t)(e * NT + tt) * 7168 + lane * 8;
        #pragma unroll
        for (int k = 0; k < 4; ++k) {
            const int i = w + 4 * k;           // wave-uniform, 0..15; 14 used
            if (i < 14) GLOAD16(bbase + i * 512, &Bw_lds[bb][i * 512]);
        }
    };

    // -------- phase A: B-dbuf + A-reg pipeline, 1 barrier per k-tile --------
    stageB(0, 0);
    loadA(0, 0);
    __syncthreads();                            // vmcnt drain -> Bw[0] ready
    #pragma unroll
    for (int kt = 0; kt < NT; ++kt) {
        const int cb = kt & 1, nb = cb ^ 1;
        if (kt < NT - 1) {
            stageB(kt + 1, nb);                 // DMA into other buffer
            loadA(kt + 1, nb);                  // regs for next tile (latency under MFMAs)
        }
        const bf16x8 axh = areg[cb][0];
        const bf16x8 axl = areg[cb][1];
        const bf16x8 ayh = areg[cb][2];
        const bf16x8 ayl = areg[cb][3];
        #pragma unroll
        for (int ni = 0; ni < 7; ++ni) {
            const bf16x8 bh = *(const bf16x8*)(&Bw_lds[cb][b_base + ni * 128]);
            const bf16x8 bl = *(const bf16x8*)(&Bw_lds[cb][b_base + ni * 128 + 3584]);
            accx[ni] = __builtin_amdgcn_mfma_f32_16x16x32_bf16(axh, bh, accx[ni], 0, 0, 0);
            accx[ni] = __builtin_amdgcn_mfma_f32_16x16x32_bf16(axl, bh, accx[ni], 0, 0, 0);
            accx[ni] = __builtin_amdgcn_mfma_f32_16x16x32_bf16(axh, bl, accx[ni], 0, 0, 0);
            accy[ni] = __builtin_amdgcn_mfma_f32_16x16x32_bf16(ayh, bh, accy[ni], 0, 0, 0);
            accy[ni] = __builtin_amdgcn_mfma_f32_16x16x32_bf16(ayl, bh, accy[ni], 0, 0, 0);
            accy[ni] = __builtin_amdgcn_mfma_f32_16x16x32_bf16(ayh, bl, accy[ni], 0, 0, 0);
        }
        __syncthreads();     // waves done with Bw[cb]; Bw[nb] staging landed
    }

    // -------- staging region dead: featl takes over. zero k-pads [202..231] ---
    for (int k = tid; k < 64 * 30; k += 256) featl[k / 30][202 + k % 30] = (_Float16)0.f;

    // -------- phase B: bias, feat, cos (frozen) --------
    float pxx[4] = {0, 0, 0, 0}, pyy[4] = {0, 0, 0, 0}, pxy[4] = {0, 0, 0, 0};
    #pragma unroll
    for (int ni = 0; ni < 7; ++ni) {
        const int c = ni * 16 + li;
        if (c < P_) {
            const float bp = b1[(size_t)e * P_ + c];
            #pragma unroll
            for (int j = 0; j < 4; ++j) {
                const float xv = accx[ni][j] + bp;
                const float yv = accy[ni][j] + bp;
                const int r = w * 16 + kgq * 4 + j;   // C-frag row (m89 layout)
                featl[r][1 + c]   = (_Float16)(xv + yv);
                featl[r][101 + c] = (_Float16)fabsf(xv - yv);
                pxx[j] += xv * xv; pyy[j] += yv * yv; pxy[j] += xv * yv;
            }
        }
    }
    #pragma unroll
    for (int j = 0; j < 4; ++j) {
        #pragma unroll
        for (int m = 1; m < 16; m <<= 1) {
            pxx[j] += __shfl_xor(pxx[j], m);
            pyy[j] += __shfl_xor(pyy[j], m);
            pxy[j] += __shfl_xor(pxy[j], m);
        }
    }
    if (li == 0) {
        #pragma unroll
        for (int j = 0; j < 4; ++j) {
            const int r = w * 16 + kgq * 4 + j;
            const float nx = fmaxf(sqrtf(pxx[j]), 1e-8f);
            const float ny = fmaxf(sqrtf(pyy[j]), 1e-8f);
            featl[r][0]   = (_Float16)(pxy[j] / (nx * ny));
            featl[r][201] = (_Float16)tag[b0 + r];
        }
    }
    __syncthreads();

    // -------- phase C: hidden (202->20) via fp16 MFMA + out (20->1) --------
    const int h1 = 16 + li;
    const bool v1 = (h1 < H_);
    const int h1c = v1 ? h1 : (H_ - 1);     // clamped in-bounds row for invalid lanes
    const _Float16* whp = wh2g + (size_t)e * 9280;

    f32x4 acc0 = (f32x4){0.f, 0.f, 0.f, 0.f};
    f32x4 acc1 = (f32x4){0.f, 0.f, 0.f, 0.f};
    #pragma unroll
    for (int kt = 0; kt < 7; ++kt) {
        const int ko = kt * 32 + kgq * 8;
        const f16x8 af = *(const f16x8*)(&featl[w * 16 + li][ko]);
        f16x8 b0h, b0l, b1h, b1l;
        if constexpr (MODE == 1) {
            b0h = *(const f16x8*)(whp + li * 232 + ko);
            b0l = *(const f16x8*)(whp + 4640 + li * 232 + ko);
            b1h = *(const f16x8*)(whp + h1c * 232 + ko);
            b1l = *(const f16x8*)(whp + 4640 + h1c * 232 + ko);
        } else {
            b0h = *(const f16x8*)(&(*swh2)[li][ko]);
            b0l = *(const f16x8*)(&swh2[1][li][ko]);
            b1h = *(const f16x8*)(&(*swh2)[h1c][ko]);
            b1l = *(const f16x8*)(&swh2[1][h1c][ko]);
        }
        if (!v1) {                              // zero pad-cols 20..31
            b1h = (f16x8)(_Float16)0.f;
            b1l = (f16x8)(_Float16)0.f;
        }
        acc0 = __builtin_amdgcn_mfma_f32_16x16x32_f16(af, b0h, acc0, 0, 0, 0);
        acc0 = __builtin_amdgcn_mfma_f32_16x16x32_f16(af, b0l, acc0, 0, 0, 0);
        acc1 = __builtin_amdgcn_mfma_f32_16x16x32_f16(af, b1h, acc1, 0, 0, 0);
        acc1 = __builtin_amdgcn_mfma_f32_16x16x32_f16(af, b1l, acc1, 0, 0, 0);
    }

    // epilogue: bias + relu + wo, reduce over h (16 lanes), write pd/out
    const float hb0 = hb[(size_t)e * H_ + li];
    const float wo0 = wo[(size_t)e * H_ + li];
    const float hb1 = v1 ? hb[(size_t)e * H_ + h1] : 0.f;
    const float wo1 = v1 ? wo[(size_t)e * H_ + h1] : 0.f;
    #pragma unroll
    for (int j = 0; j < 4; ++j) {
        float t = fmaxf(acc0[j] + hb0, 0.f) * wo0;
        if (v1) t += fmaxf(acc1[j] + hb1, 0.f) * wo1;
        t += __shfl_xor(t, 1);
        t += __shfl_xor(t, 2);
        t += __shfl_xor(t, 4);
        t += __shfl_xor(t, 8);
        if (li == 0) {
            const int r = w * 16 + kgq * 4 + j;   // C-frag row
            const int b = b0 + r;
            const float v = wgate[(size_t)b * E_ + e] * (t + ob[e]);
            if (MODE == 1) pd[(size_t)e * B_ + b] = v;
            else           atomicAdd(&out[b], v);
        }
    }
}

// ---------------------------------------------------------------------------
// deterministic reduction over experts (fixed e-ascending order)
// ---------------------------------------------------------------------------
__global__ __launch_bounds__(256) void reduce_kernel(const float* __restrict__ pd,
                                                     float* __restrict__ out)
{
    const int b = blockIdx.x * 256 + threadIdx.x;
    float s = 0.f;
    for (int e = 0; e < E_; ++e) s += pd[(size_t)e * B_ + b];
    out[b] = s;
}

// ---------------------------------------------------------------------------
extern "C" void kernel_launch(void* const* d_in, const int* in_sizes, int n_in,
                              void* d_out, int out_size, void* d_ws, size_t ws_size,
                              hipStream_t stream)
{
    const float* x    = (const float*)d_in[0];
    const float* y    = (const float*)d_in[1];
    const float* tag  = (const float*)d_in[2];
    const float* w1   = (const float*)d_in[3];
    const float* b1   = (const float*)d_in[4];
    const float* wh   = (const float*)d_in[5];
    const float* hb   = (const float*)d_in[6];
    const float* wo   = (const float*)d_in[7];
    const float* ob   = (const float*)d_in[8];
    const float* wall = (const float*)d_in[9];

    float* out = (float*)d_out;
    char* ws = (char*)d_ws;
    float*          wgate = (float*)(ws + WG_OFF);
    unsigned short* ab2   = (unsigned short*)(ws + AB_OFF);
    unsigned short* w1b2  = (unsigned short*)(ws + W1_OFF);
    _Float16*       wh2   = (_Float16*)(ws + WH2_OFF);
    float*          pd    = (float*)(ws + PD_OFF);

    const bool full = (ws_size >= (size_t)WS_ALL);

    prep_xy<<<dim3(128 * NT), dim3(256), 0, stream>>>(x, y, ab2);
    prep_w1<<<dim3(E_ * NT), dim3(256), 0, stream>>>(w1, w1b2);
    gate_kernel<<<dim3(B_), dim3(128), 0, stream>>>(x, y, wall, wgate);

    if (full) {
        prep_wh<<<dim3(E_), dim3(256), 0, stream>>>(wh, wh2);
        moe_mfma_kernel<1><<<dim3(NWG), dim3(256), 0, stream>>>(
            tag, ab2, w1b2, wh2, b1, wh, hb, wo, ob, wgate, pd, out);
        reduce_kernel<<<dim3(B_ / 256), dim3(256), 0, stream>>>(pd, out);
    } else {
        hipMemsetAsync(out, 0, (size_t)B_ * sizeof(float), stream);
        moe_mfma_kernel<0><<<dim3(NWG), dim3(256), 0, stream>>>(
            tag, ab2, w1b2, wh2, b1, wh, hb, wo, ob, wgate, pd, out);
    }
}